// Round 1
// baseline (223.008 us; speedup 1.0000x reference)
//
#include <hip/hip_runtime.h>
#include <hip/hip_cooperative_groups.h>

namespace cg = cooperative_groups;

// Problem constants (fixed by reference setup): B=8, X=Y=Z=128, P=64.
#define BATCH     8
#define DIM       128
#define NVOX      (BATCH * DIM * DIM * DIM)       // 16,777,216 floats
#define NPERSON   64
#define THREADS   256
#define FLOATS_PER_BLOCK 32768                    // 8192 float4 per dense block
#define NBLOCK_DENSE (NVOX / FLOATS_PER_BLOCK)    // 512 dense blocks (64/batch)
#define NPARTIAL  (NBLOCK_DENSE * 4)              // one partial per wave = 2048
#define TSIZE     4096
#define EMPTYK    0xFFFFFFFFu
#define KEYMASK   0x00FFFFFFu
#define HEATBIT   0x40000000u

// d_ws layout: [0..2047] per-wave sumsq partials (batch b owns [b*256, b*256+256)).
// Every slot is written unconditionally before grid.sync -> no zeroing needed.
// Sparse scalars never leave block 0's LDS (block 0 is also the combiner).

// ---------------------------------------------------------------------------
// Single cooperative kernel:
//   block 0          = sparse person/dilation work (latency-pipelined),
//   blocks 1..512    = dense sumsq sweep (one partial store per wave),
//   grid.sync(),
//   block 0          = final combine straight out of its own LDS.
// ---------------------------------------------------------------------------
__global__ __launch_bounds__(THREADS) void person_loss_fused(
    const float* __restrict__ feature,
    const float* __restrict__ batch_index,
    const float* __restrict__ person_pos,
    const float* __restrict__ min_loc,
    const float* __restrict__ delta,
    float* __restrict__ ws,
    float* __restrict__ out)
{
    __shared__ unsigned keys[NPERSON];
    __shared__ int      uniq[NPERSON];
    __shared__ float    lDil[BATCH], lCorr[BATCH], lPos[BATCH];
    __shared__ int      lNr[BATCH];
    __shared__ unsigned table[TSIZE];
    __shared__ float    sums[BATCH];

    const int tid  = threadIdx.x;
    const int bid  = blockIdx.x;
    const int lane = tid & 63, wave = tid >> 6;

    if (bid != 0) {
        // ---------------- dense path: partial sum of feature^2 ----------------
        const float4* f4 = (const float4*)feature;
        const size_t base = (size_t)(bid - 1) * (FLOATS_PER_BLOCK / 4);
        float acc = 0.f;
#pragma unroll
        for (int c = 0; c < 4; ++c) {
            float4 v[8];
#pragma unroll
            for (int j = 0; j < 8; ++j)
                v[j] = f4[base + (size_t)(c * 8 + j) * THREADS + tid];
#pragma unroll
            for (int j = 0; j < 8; ++j)
                acc += v[j].x * v[j].x + v[j].y * v[j].y
                     + v[j].z * v[j].z + v[j].w * v[j].w;
        }
        for (int off = 32; off > 0; off >>= 1) acc += __shfl_down(acc, off, 64);
        if (lane == 0) ws[(bid - 1) * 4 + wave] = acc;   // per-wave partial
    } else {
        // ---------------- sparse path (block 0) ----------------
        if (tid < BATCH) { lDil[tid] = 0.f; lCorr[tid] = 0.f; lPos[tid] = 0.f; lNr[tid] = 0; }
        for (int s = tid; s < TSIZE; s += THREADS) table[s] = EMPTYK;

        if (tid < NPERSON) {
            const int p = tid;
            const int b = (int)(batch_index[p] + 0.5f);
            float vx = (person_pos[p * 3 + 0] - min_loc[0]) / delta[0];
            float vy = (person_pos[p * 3 + 1] - min_loc[1]) / delta[1];
            float vz = (person_pos[p * 3 + 2] - min_loc[2]) / delta[2];
            vx = fminf(fmaxf(vx, 0.f), (float)(DIM - 1));
            vy = fminf(fmaxf(vy, 0.f), (float)(DIM - 1));
            vz = fminf(fmaxf(vz, 0.f), (float)(DIM - 1));
            const int x = (int)(vx + 0.5f);
            const int y = (int)(vy + 0.5f);
            const int z = (int)(vz + 0.5f);
            keys[p] = ((unsigned)b << 21) | ((unsigned)x << 14) | ((unsigned)y << 7) | (unsigned)z;
        }
        __syncthreads();

        // dedup persons — fixed 64-trip loop (no break) so LDS reads pipeline
        if (tid < NPERSON) {
            const unsigned mykey = keys[tid];
            int u = 1;
#pragma unroll
            for (int q = 0; q < NPERSON; ++q) {
                if (q < tid && keys[q] == mykey) u = 0;
            }
            uniq[tid] = u;
            if (u) atomicAdd(&lNr[mykey >> 21], 1);   // LDS atomic
        }
        __syncthreads();

        // insert 3x3x3 dilation neighborhood into LDS hash (dedup via CAS)
        for (int w = tid; w < NPERSON * 27; w += THREADS) {
            const int p = w / 27;
            if (!uniq[p]) continue;
            const unsigned k = keys[p];
            const int o = w % 27;
            const int x = (int)((k >> 14) & 127) + (o / 9) - 1;
            const int y = (int)((k >> 7) & 127) + ((o / 3) % 3) - 1;
            const int z = (int)(k & 127) + (o % 3) - 1;
            if ((unsigned)x > (unsigned)(DIM - 1) || (unsigned)y > (unsigned)(DIM - 1) ||
                (unsigned)z > (unsigned)(DIM - 1)) continue;
            const unsigned nk = (k & (7u << 21)) | ((unsigned)x << 14) | ((unsigned)y << 7) | (unsigned)z;
            unsigned h = ((nk * 2654435761u) >> 16) & (TSIZE - 1);
            for (;;) {
                const unsigned old = atomicCAS(&table[h], EMPTYK, nk);
                if (old == EMPTYK || (old & KEYMASK) == nk) break;
                h = (h + 1) & (TSIZE - 1);
            }
        }
        __syncthreads();

        // mark heat voxels: each unique person ORs HEATBIT into its entry
        if (tid < NPERSON && uniq[tid]) {
            const unsigned k = keys[tid];
            unsigned h = ((k * 2654435761u) >> 16) & (TSIZE - 1);
            for (;;) {
                const unsigned e = table[h];
                if (e != EMPTYK && (e & KEYMASK) == k) { atomicOr(&table[h], HEATBIT); break; }
                h = (h + 1) & (TSIZE - 1);
            }
        }
        __syncthreads();

        // gather: two chunks of 8 slots/thread; entry reads and global loads are
        // hoisted & independent so each chunk pays ~one HBM latency total
#pragma unroll
        for (int c = 0; c < 2; ++c) {
            unsigned e[8];
#pragma unroll
            for (int j = 0; j < 8; ++j)
                e[j] = table[(c * 8 + j) * THREADS + tid];

            float f[8];
#pragma unroll
            for (int j = 0; j < 8; ++j) {
                f[j] = 0.f;
                if (e[j] != EMPTYK) {
                    const unsigned k = e[j];
                    const int b = (k >> 21) & 7;
                    const int x = (k >> 14) & 127, y = (k >> 7) & 127, z = k & 127;
                    f[j] = feature[(((size_t)b * DIM + x) * DIM + y) * DIM + z];
                }
            }
#pragma unroll
            for (int j = 0; j < 8; ++j) {
                if (e[j] == EMPTYK) continue;
                const int b = (e[j] >> 21) & 7;
                const float heat = (e[j] & HEATBIT) ? 1.f : 0.f;
                const float d = f[j] - heat;
                atomicAdd(&lDil[b], d * d);
                if (e[j] & HEATBIT) {
                    atomicAdd(&lCorr[b], 1.f - 2.f * f[j]);
                    const float dp = f[j] - 1.f;
                    atomicAdd(&lPos[b], dp * dp);
                }
            }
        }
        __syncthreads();
    }

    // device-scope release of the partial stores, then grid-wide rendezvous
    __threadfence();
    cg::this_grid().sync();

    if (bid == 0) {
        // combine: 2048 partials, 8 per thread as two float4 loads (L2-hot),
        // 32-lane group reduction (256 partials per batch -> 32 threads/batch)
        const float4* w4 = (const float4*)ws;
        const float4 a = w4[2 * tid];
        const float4 b = w4[2 * tid + 1];
        float s = a.x + a.y + a.z + a.w + b.x + b.y + b.z + b.w;
        for (int off = 16; off > 0; off >>= 1) s += __shfl_down(s, off, 32);
        if ((tid & 31) == 0) sums[tid >> 5] = s;
        __syncthreads();

        if (tid < BATCH) {
            const float sS2 = sums[tid];
            const float nr  = (float)lNr[tid];
            const float N   = (float)(DIM * DIM * DIM);
            const float scale_neg = nr * 27.f / N;
            const float scale_pos = 1.f - nr / N;
            const float neg = sS2 + lCorr[tid] - lDil[tid];
            out[tid] = (scale_neg * neg + scale_pos * lPos[tid]) / nr;
        }
    }
}

extern "C" void kernel_launch(void* const* d_in, const int* in_sizes, int n_in,
                              void* d_out, int out_size, void* d_ws, size_t ws_size,
                              hipStream_t stream)
{
    const float* feature     = (const float*)d_in[0];
    const float* batch_index = (const float*)d_in[1];
    const float* person_pos  = (const float*)d_in[2];
    const float* min_loc     = (const float*)d_in[3];
    const float* delta       = (const float*)d_in[4];
    float* out = (float*)d_out;
    float* ws  = (float*)d_ws;

    void* args[] = { &feature, &batch_index, &person_pos, &min_loc, &delta, &ws, &out };
    hipLaunchCooperativeKernel(person_loss_fused,
                               dim3(NBLOCK_DENSE + 1), dim3(THREADS),
                               args, 0, stream);
}

// Round 2
// 155.638 us; speedup vs baseline: 1.4329x; 1.4329x over previous
//
#include <hip/hip_runtime.h>

// Problem constants (fixed by reference setup): B=8, X=Y=Z=128, P=64.
#define BATCH     8
#define DIM       128
#define NVOX      (BATCH * DIM * DIM * DIM)       // 16,777,216 floats
#define NPERSON   64
#define THREADS   256
#define FLOATS_PER_BLOCK 8192                     // 2048 float4 per dense block
#define NBLOCK1   (NVOX / FLOATS_PER_BLOCK)       // 2048 dense blocks (256/batch)
#define TSIZE     4096
#define EMPTYK    0xFFFFFFFFu
#define KEYMASK   0x00FFFFFFu
#define HEATBIT   0x40000000u

// d_ws float layout:
//   [0..2047]    per-block sumsq partials (batch b owns [b*256, b*256+256))
//   [2048..2055] Sdil per batch
//   [2056..2063] Scorr per batch
//   [2064..2071] Spos per batch
//   [2072..2079] nr_persons per batch (as float)
//   [2080]       arrival counter (u32) — zeroed by hipMemsetAsync each launch
#define WS_DIL   2048
#define WS_CORR  2056
#define WS_POS   2064
#define WS_NR    2072
#define WS_CTR   2080

// ---------------------------------------------------------------------------
// Single launch: block 0 = sparse person/dilation work; blocks 1..2048 =
// dense sumsq sweep (round-0 geometry: 8 blocks/CU, 8 float4 in flight per
// thread -> ~4 KB outstanding per CU, the proven latency-hiding point).
// Last block to arrive (rocPRIM-style ticket) does the final combine while
// partials are L2-hot. No second kernel, no cooperative launch.
// ---------------------------------------------------------------------------
__global__ __launch_bounds__(THREADS) void person_loss_main(
    const float* __restrict__ feature,
    const float* __restrict__ batch_index,
    const float* __restrict__ person_pos,
    const float* __restrict__ min_loc,
    const float* __restrict__ delta,
    float* __restrict__ ws,
    float* __restrict__ out)
{
    __shared__ unsigned keys[NPERSON];
    __shared__ int      uniq[NPERSON];
    __shared__ float    lDil[BATCH], lCorr[BATCH], lPos[BATCH];
    __shared__ int      lNr[BATCH];
    __shared__ unsigned table[TSIZE];
    __shared__ float    red[4];
    __shared__ float    red2[BATCH][4];
    __shared__ int      isLast;

    const int tid  = threadIdx.x;
    const int bid  = blockIdx.x;
    const int lane = tid & 63, wave = tid >> 6;

    if (bid != 0) {
        // ---------------- dense path: partial sum of feature^2 ----------------
        const float4* f4 = (const float4*)feature;
        const size_t base = (size_t)(bid - 1) * (FLOATS_PER_BLOCK / 4);
        float acc = 0.f;
#pragma unroll
        for (int j = 0; j < 8; ++j) {
            float4 v = f4[base + (size_t)j * THREADS + tid];
            acc += v.x * v.x + v.y * v.y + v.z * v.z + v.w * v.w;
        }
        for (int off = 32; off > 0; off >>= 1) acc += __shfl_down(acc, off, 64);
        if (lane == 0) red[wave] = acc;
        __syncthreads();
        if (tid == 0) ws[bid - 1] = red[0] + red[1] + red[2] + red[3];
    } else {
        // ---------------- sparse path (block 0) ----------------
        if (tid < BATCH) { lDil[tid] = 0.f; lCorr[tid] = 0.f; lPos[tid] = 0.f; lNr[tid] = 0; }
        for (int s = tid; s < TSIZE; s += THREADS) table[s] = EMPTYK;

        if (tid < NPERSON) {
            const int p = tid;
            const int b = (int)(batch_index[p] + 0.5f);
            float vx = (person_pos[p * 3 + 0] - min_loc[0]) / delta[0];
            float vy = (person_pos[p * 3 + 1] - min_loc[1]) / delta[1];
            float vz = (person_pos[p * 3 + 2] - min_loc[2]) / delta[2];
            vx = fminf(fmaxf(vx, 0.f), (float)(DIM - 1));
            vy = fminf(fmaxf(vy, 0.f), (float)(DIM - 1));
            vz = fminf(fmaxf(vz, 0.f), (float)(DIM - 1));
            const int x = (int)(vx + 0.5f);
            const int y = (int)(vy + 0.5f);
            const int z = (int)(vz + 0.5f);
            keys[p] = ((unsigned)b << 21) | ((unsigned)x << 14) | ((unsigned)y << 7) | (unsigned)z;
        }
        __syncthreads();

        // dedup persons — fixed 64-trip loop (no break) so LDS reads pipeline
        if (tid < NPERSON) {
            const unsigned mykey = keys[tid];
            int u = 1;
#pragma unroll
            for (int q = 0; q < NPERSON; ++q) {
                if (q < tid && keys[q] == mykey) u = 0;
            }
            uniq[tid] = u;
            if (u) atomicAdd(&lNr[mykey >> 21], 1);   // LDS atomic
        }
        __syncthreads();

        // insert 3x3x3 dilation neighborhood into LDS hash (dedup via CAS)
        for (int w = tid; w < NPERSON * 27; w += THREADS) {
            const int p = w / 27;
            if (!uniq[p]) continue;
            const unsigned k = keys[p];
            const int o = w % 27;
            const int x = (int)((k >> 14) & 127) + (o / 9) - 1;
            const int y = (int)((k >> 7) & 127) + ((o / 3) % 3) - 1;
            const int z = (int)(k & 127) + (o % 3) - 1;
            if ((unsigned)x > (unsigned)(DIM - 1) || (unsigned)y > (unsigned)(DIM - 1) ||
                (unsigned)z > (unsigned)(DIM - 1)) continue;
            const unsigned nk = (k & (7u << 21)) | ((unsigned)x << 14) | ((unsigned)y << 7) | (unsigned)z;
            unsigned h = ((nk * 2654435761u) >> 16) & (TSIZE - 1);
            for (;;) {
                const unsigned old = atomicCAS(&table[h], EMPTYK, nk);
                if (old == EMPTYK || (old & KEYMASK) == nk) break;
                h = (h + 1) & (TSIZE - 1);
            }
        }
        __syncthreads();

        // mark heat voxels: each unique person ORs HEATBIT into its entry
        if (tid < NPERSON && uniq[tid]) {
            const unsigned k = keys[tid];
            unsigned h = ((k * 2654435761u) >> 16) & (TSIZE - 1);
            for (;;) {
                const unsigned e = table[h];
                if (e != EMPTYK && (e & KEYMASK) == k) { atomicOr(&table[h], HEATBIT); break; }
                h = (h + 1) & (TSIZE - 1);
            }
        }
        __syncthreads();

        // gather: two chunks of 8 slots/thread; entry reads and global loads are
        // hoisted & independent so each chunk pays ~one HBM latency total
#pragma unroll
        for (int c = 0; c < 2; ++c) {
            unsigned e[8];
#pragma unroll
            for (int j = 0; j < 8; ++j)
                e[j] = table[(c * 8 + j) * THREADS + tid];

            float f[8];
#pragma unroll
            for (int j = 0; j < 8; ++j) {
                f[j] = 0.f;
                if (e[j] != EMPTYK) {
                    const unsigned k = e[j];
                    const int b = (k >> 21) & 7;
                    const int x = (k >> 14) & 127, y = (k >> 7) & 127, z = k & 127;
                    f[j] = feature[(((size_t)b * DIM + x) * DIM + y) * DIM + z];
                }
            }
#pragma unroll
            for (int j = 0; j < 8; ++j) {
                if (e[j] == EMPTYK) continue;
                const int b = (e[j] >> 21) & 7;
                const float heat = (e[j] & HEATBIT) ? 1.f : 0.f;
                const float d = f[j] - heat;
                atomicAdd(&lDil[b], d * d);
                if (e[j] & HEATBIT) {
                    atomicAdd(&lCorr[b], 1.f - 2.f * f[j]);
                    const float dp = f[j] - 1.f;
                    atomicAdd(&lPos[b], dp * dp);
                }
            }
        }
        __syncthreads();

        if (tid < BATCH) {
            ws[WS_DIL  + tid] = lDil[tid];
            ws[WS_CORR + tid] = lCorr[tid];
            ws[WS_POS  + tid] = lPos[tid];
            ws[WS_NR   + tid] = (float)lNr[tid];
        }
        __syncthreads();   // make tid<8 stores issue before tid0's release fence
    }

    // ---------------- last-block-done rendezvous (rocPRIM pattern) ----------
    // Release: all this block's global stores have drained (the __syncthreads
    // above emits s_waitcnt vmcnt(0)); tid0's device fence publishes them,
    // then the device-scope atomic ticket signals arrival.
    if (tid == 0) {
        __threadfence();
        const unsigned old = atomicAdd((unsigned int*)(ws + WS_CTR), 1u);
        isLast = (old == (unsigned)NBLOCK1);   // 2049th arrival
    }
    __syncthreads();
    if (!isLast) return;

    // Acquire: invalidate caches before reading other blocks' partials.
    __threadfence();

    // combine: 2048 partials, batch b owns ws[b*256 + tid]; 64-wide reduce
    float v[BATCH];
#pragma unroll
    for (int b = 0; b < BATCH; ++b) v[b] = ws[b * (NBLOCK1 / BATCH) + tid];

#pragma unroll
    for (int b = 0; b < BATCH; ++b) {
        float s = v[b];
        for (int off = 32; off > 0; off >>= 1) s += __shfl_down(s, off, 64);
        if (lane == 0) red2[b][wave] = s;
    }
    __syncthreads();

    if (tid < BATCH) {
        const int b = tid;
        const float sS2 = red2[b][0] + red2[b][1] + red2[b][2] + red2[b][3];
        const float nr  = ws[WS_NR + b];
        const float N = (float)(DIM * DIM * DIM);
        const float scale_neg = nr * 27.f / N;
        const float scale_pos = 1.f - nr / N;
        const float neg = sS2 + ws[WS_CORR + b] - ws[WS_DIL + b];
        out[b] = (scale_neg * neg + scale_pos * ws[WS_POS + b]) / nr;
    }
}

extern "C" void kernel_launch(void* const* d_in, const int* in_sizes, int n_in,
                              void* d_out, int out_size, void* d_ws, size_t ws_size,
                              hipStream_t stream)
{
    const float* feature     = (const float*)d_in[0];
    const float* batch_index = (const float*)d_in[1];
    const float* person_pos  = (const float*)d_in[2];
    const float* min_loc     = (const float*)d_in[3];
    const float* delta       = (const float*)d_in[4];
    float* out = (float*)d_out;
    float* ws  = (float*)d_ws;

    // zero the arrival counter (ws is poisoned between runs; 4-byte memset
    // node is graph-capturable — the harness itself enqueues memset nodes)
    hipMemsetAsync((char*)ws + WS_CTR * sizeof(float), 0, sizeof(unsigned int), stream);

    person_loss_main<<<NBLOCK1 + 1, THREADS, 0, stream>>>(
        feature, batch_index, person_pos, min_loc, delta, ws, out);
}

// Round 3
// 99.373 us; speedup vs baseline: 2.2441x; 1.5662x over previous
//
#include <hip/hip_runtime.h>

// Problem constants (fixed by reference setup): B=8, X=Y=Z=128, P=64.
#define BATCH     8
#define DIM       128
#define NVOX      (BATCH * DIM * DIM * DIM)       // 16,777,216 floats
#define NPERSON   64
#define THREADS   256
#define FLOATS_PER_BLOCK 8192                     // 2048 float4
#define NBLOCK1   (NVOX / FLOATS_PER_BLOCK)       // 2048 dense blocks (256/batch)
#define TSIZE     4096
#define EMPTYK    0xFFFFFFFFu
#define KEYMASK   0x00FFFFFFu
#define HEATBIT   0x40000000u

// d_ws float layout (plain stores only; coherence via kernel boundary):
//   [0..2047]    per-block sumsq partials (batch b owns [b*256, b*256+256))
//   [2048..2055] Sdil per batch
//   [2056..2063] Scorr per batch
//   [2064..2071] Spos per batch
//   [2072..2079] nr_persons per batch (as float)
// No zeroing needed: every slot read by kernel B is written unconditionally.
//
// SESSION NOTE (do not "optimize" the two-kernel split away):
//   R1 cooperative grid.sync single-kernel:      223 µs  (latency collapse @ 2 blk/CU)
//   R2 last-block ticket (fence+atomic/block):   156 µs  (~35 µs per 1000 blocks of
//      device-scope __threadfence + same-address atomics across 8 XCD L2s)
//   R0 two-kernel, coherence via kernel boundary: 101 µs  <- this structure
#define WS_DIL   2048
#define WS_CORR  2056
#define WS_POS   2064
#define WS_NR    2072

// ---------------------------------------------------------------------------
// Kernel A: block 0 = sparse person/dilation work (latency-pipelined);
//           blocks 1..2048 = dense sumsq sweep. No global atomics/fences.
// ---------------------------------------------------------------------------
__global__ __launch_bounds__(THREADS) void person_loss_main(
    const float* __restrict__ feature,
    const float* __restrict__ batch_index,
    const float* __restrict__ person_pos,
    const float* __restrict__ min_loc,
    const float* __restrict__ delta,
    float* __restrict__ ws)
{
    __shared__ unsigned keys[NPERSON];
    __shared__ int      uniq[NPERSON];
    __shared__ float    lDil[BATCH], lCorr[BATCH], lPos[BATCH];
    __shared__ int      lNr[BATCH];
    __shared__ unsigned table[TSIZE];
    __shared__ float    red[4];

    const int tid  = threadIdx.x;
    const int bid  = blockIdx.x;
    const int lane = tid & 63, wave = tid >> 6;

    if (bid != 0) {
        // ---------------- dense path: partial sum of feature^2 ----------------
        const float4* f4 = (const float4*)feature;
        const size_t base = (size_t)(bid - 1) * (FLOATS_PER_BLOCK / 4);
        float acc = 0.f;
#pragma unroll
        for (int j = 0; j < 8; ++j) {
            float4 v = f4[base + (size_t)j * THREADS + tid];
            acc += v.x * v.x + v.y * v.y + v.z * v.z + v.w * v.w;
        }
        for (int off = 32; off > 0; off >>= 1) acc += __shfl_down(acc, off, 64);
        if (lane == 0) red[wave] = acc;
        __syncthreads();
        if (tid == 0) ws[bid - 1] = red[0] + red[1] + red[2] + red[3];
        return;
    }

    // ---------------- sparse path (block 0) ----------------
    if (tid < BATCH) { lDil[tid] = 0.f; lCorr[tid] = 0.f; lPos[tid] = 0.f; lNr[tid] = 0; }
    for (int s = tid; s < TSIZE; s += THREADS) table[s] = EMPTYK;

    if (tid < NPERSON) {
        const int p = tid;
        const int b = (int)(batch_index[p] + 0.5f);
        float vx = (person_pos[p * 3 + 0] - min_loc[0]) / delta[0];
        float vy = (person_pos[p * 3 + 1] - min_loc[1]) / delta[1];
        float vz = (person_pos[p * 3 + 2] - min_loc[2]) / delta[2];
        vx = fminf(fmaxf(vx, 0.f), (float)(DIM - 1));
        vy = fminf(fmaxf(vy, 0.f), (float)(DIM - 1));
        vz = fminf(fmaxf(vz, 0.f), (float)(DIM - 1));
        const int x = (int)(vx + 0.5f);
        const int y = (int)(vy + 0.5f);
        const int z = (int)(vz + 0.5f);
        keys[p] = ((unsigned)b << 21) | ((unsigned)x << 14) | ((unsigned)y << 7) | (unsigned)z;
    }
    __syncthreads();

    // dedup persons — fixed 64-trip loop (no break) so LDS reads pipeline
    if (tid < NPERSON) {
        const unsigned mykey = keys[tid];
        int u = 1;
#pragma unroll
        for (int q = 0; q < NPERSON; ++q) {
            if (q < tid && keys[q] == mykey) u = 0;
        }
        uniq[tid] = u;
        if (u) atomicAdd(&lNr[mykey >> 21], 1);   // LDS atomic
    }
    __syncthreads();

    // insert 3x3x3 dilation neighborhood into LDS hash (dedup via CAS)
    for (int w = tid; w < NPERSON * 27; w += THREADS) {
        const int p = w / 27;
        if (!uniq[p]) continue;
        const unsigned k = keys[p];
        const int o = w % 27;
        const int x = (int)((k >> 14) & 127) + (o / 9) - 1;
        const int y = (int)((k >> 7) & 127) + ((o / 3) % 3) - 1;
        const int z = (int)(k & 127) + (o % 3) - 1;
        if ((unsigned)x > (unsigned)(DIM - 1) || (unsigned)y > (unsigned)(DIM - 1) ||
            (unsigned)z > (unsigned)(DIM - 1)) continue;
        const unsigned nk = (k & (7u << 21)) | ((unsigned)x << 14) | ((unsigned)y << 7) | (unsigned)z;
        unsigned h = ((nk * 2654435761u) >> 16) & (TSIZE - 1);
        for (;;) {
            const unsigned old = atomicCAS(&table[h], EMPTYK, nk);
            if (old == EMPTYK || (old & KEYMASK) == nk) break;
            h = (h + 1) & (TSIZE - 1);
        }
    }
    __syncthreads();

    // mark heat voxels: each unique person ORs HEATBIT into its entry
    if (tid < NPERSON && uniq[tid]) {
        const unsigned k = keys[tid];
        unsigned h = ((k * 2654435761u) >> 16) & (TSIZE - 1);
        for (;;) {
            const unsigned e = table[h];
            if (e != EMPTYK && (e & KEYMASK) == k) { atomicOr(&table[h], HEATBIT); break; }
            h = (h + 1) & (TSIZE - 1);
        }
    }
    __syncthreads();

    // gather: two chunks of 8 slots/thread; entry reads and global loads are
    // hoisted & independent so each chunk pays ~one HBM latency total
#pragma unroll
    for (int c = 0; c < 2; ++c) {
        unsigned e[8];
#pragma unroll
        for (int j = 0; j < 8; ++j)
            e[j] = table[(c * 8 + j) * THREADS + tid];

        float f[8];
#pragma unroll
        for (int j = 0; j < 8; ++j) {
            f[j] = 0.f;
            if (e[j] != EMPTYK) {
                const unsigned k = e[j];
                const int b = (k >> 21) & 7;
                const int x = (k >> 14) & 127, y = (k >> 7) & 127, z = k & 127;
                f[j] = feature[(((size_t)b * DIM + x) * DIM + y) * DIM + z];
            }
        }
#pragma unroll
        for (int j = 0; j < 8; ++j) {
            if (e[j] == EMPTYK) continue;
            const int b = (e[j] >> 21) & 7;
            const float heat = (e[j] & HEATBIT) ? 1.f : 0.f;
            const float d = f[j] - heat;
            atomicAdd(&lDil[b], d * d);
            if (e[j] & HEATBIT) {
                atomicAdd(&lCorr[b], 1.f - 2.f * f[j]);
                const float dp = f[j] - 1.f;
                atomicAdd(&lPos[b], dp * dp);
            }
        }
    }
    __syncthreads();

    if (tid < BATCH) {
        ws[WS_DIL  + tid] = lDil[tid];
        ws[WS_CORR + tid] = lCorr[tid];
        ws[WS_POS  + tid] = lPos[tid];
        ws[WS_NR   + tid] = (float)lNr[tid];
    }
}

// ---------------------------------------------------------------------------
// Kernel B: single tiny block. All 8x256 partial loads issued up-front
// (independent -> one LLC latency), register wave-reduction, ONE barrier.
// ---------------------------------------------------------------------------
__global__ __launch_bounds__(THREADS) void person_loss_combine(
    const float* __restrict__ ws, float* __restrict__ out)
{
    __shared__ float red[BATCH][4];
    const int tid = threadIdx.x;
    const int lane = tid & 63, wave = tid >> 6;

    // 8 independent loads per thread (one per batch segment)
    float v[BATCH];
#pragma unroll
    for (int b = 0; b < BATCH; ++b) v[b] = ws[b * (NBLOCK1 / BATCH) + tid];

#pragma unroll
    for (int b = 0; b < BATCH; ++b) {
        float s = v[b];
        for (int off = 32; off > 0; off >>= 1) s += __shfl_down(s, off, 64);
        if (lane == 0) red[b][wave] = s;
    }
    __syncthreads();

    if (tid < BATCH) {
        const int b = tid;
        const float sS2 = red[b][0] + red[b][1] + red[b][2] + red[b][3];
        const float nr  = ws[WS_NR + b];
        const float N = (float)(DIM * DIM * DIM);
        const float scale_neg = nr * 27.f / N;
        const float scale_pos = 1.f - nr / N;
        const float neg = sS2 + ws[WS_CORR + b] - ws[WS_DIL + b];
        out[b] = (scale_neg * neg + scale_pos * ws[WS_POS + b]) / nr;
    }
}

extern "C" void kernel_launch(void* const* d_in, const int* in_sizes, int n_in,
                              void* d_out, int out_size, void* d_ws, size_t ws_size,
                              hipStream_t stream)
{
    const float* feature     = (const float*)d_in[0];
    const float* batch_index = (const float*)d_in[1];
    const float* person_pos  = (const float*)d_in[2];
    const float* min_loc     = (const float*)d_in[3];
    const float* delta       = (const float*)d_in[4];
    float* out = (float*)d_out;
    float* ws  = (float*)d_ws;

    person_loss_main<<<NBLOCK1 + 1, THREADS, 0, stream>>>(
        feature, batch_index, person_pos, min_loc, delta, ws);
    person_loss_combine<<<1, THREADS, 0, stream>>>(ws, out);
}